// Round 1
// baseline (356.347 us; speedup 1.0000x reference)
//
#include <hip/hip_runtime.h>
#include <hip/hip_bf16.h>
#include <cstdint>
#include <cstddef>

#define DEVI __device__ __forceinline__

typedef unsigned short u16;
using frag_ab = __attribute__((ext_vector_type(8))) short;   // 8 bf16 (4 VGPRs)
using f32x4   = __attribute__((ext_vector_type(4))) float;   // mfma acc

constexpr int HW = 16384;   // 128*128 spatial
constexpr int NC = 256;     // channels (Cin = Cout = 256)

DEVI u16 bf16bits(float f) {
    union { float f; uint32_t u; } cv; cv.f = f;
    uint32_t u = cv.u;
    u += 0x7fffu + ((u >> 16) & 1u);   // RNE
    return (u16)(u >> 16);
}

DEVI void gload16(const void* g, void* l) {
    __builtin_amdgcn_global_load_lds(
        (const __attribute__((address_space(1))) uint32_t*)g,
        (__attribute__((address_space(3))) uint32_t*)l, 16, 0, 0);
}

// LDS slab layout: [row][64B k-slice], slot s (16B) stored at phys slot s ^ (row&3) ^ ((row>>2)&3)
// -> ds_read_b128 frag loads are 2-way bank-aliased (free, m136).
DEVI frag_ab read_frag(const u16* slab, int row, int l4) {
    const int phys = (l4 ^ row ^ (row >> 2)) & 3;
    return *(const frag_ab*)((const char*)slab + row * 64 + phys * 16);
}

// ---------------- pass 1: x stats + transpose to xt[b][p][c] bf16 ----------------
__global__ __launch_bounds__(256) void transpose_stats_kernel(
    const float* __restrict__ x, u16* __restrict__ xt,
    float* __restrict__ sum, float* __restrict__ sq)
{
    __shared__ __align__(16) u16 tile[64][72];   // [p][c], pad 72 keeps rows 16B-multiple
    const int b = blockIdx.z, c0 = blockIdx.y * 64, p0 = blockIdx.x * 64;
    const int t = threadIdx.x;
    const int f = t & 15, cw = t >> 4;
    const float* xb = x + ((size_t)b * NC + c0) * HW + p0;
    #pragma unroll
    for (int pass = 0; pass < 4; ++pass) {
        const int cl = cw + pass * 16;
        const float4 v = *(const float4*)(xb + (size_t)cl * HW + f * 4);
        float s1 = v.x + v.y + v.z + v.w;
        float s2 = v.x*v.x + v.y*v.y + v.z*v.z + v.w*v.w;
        #pragma unroll
        for (int d = 1; d < 16; d <<= 1) {
            s1 += __shfl_xor(s1, d, 64);
            s2 += __shfl_xor(s2, d, 64);
        }
        if (f == 0) {
            atomicAdd(&sum[b*NC + c0 + cl], s1);
            atomicAdd(&sq [b*NC + c0 + cl], s2);
        }
        tile[f*4+0][cl] = bf16bits(v.x);
        tile[f*4+1][cl] = bf16bits(v.y);
        tile[f*4+2][cl] = bf16bits(v.z);
        tile[f*4+3][cl] = bf16bits(v.w);
    }
    __syncthreads();
    const int pl = t >> 2, q = t & 3;
    u16* dst = xt + ((size_t)b * HW + p0 + pl) * NC + c0;
    #pragma unroll
    for (int s = 0; s < 2; ++s) {
        const int ch = q + s * 4;
        *(uint4*)(dst + ch * 8) = *(const uint4*)(&tile[pl][ch * 8]);
    }
}

// ---------------- fold: IN folded into conv weights/bias ----------------
// we[b][o][c] = w[o][c]*rs[b][c] (bf16), be[b][o] = bias[o] - sum_c w[o][c]*mu[b][c]*rs[b][c]
__global__ __launch_bounds__(256) void fold_kernel(
    const float* __restrict__ w, const float* __restrict__ bias,
    const float* __restrict__ sum, const float* __restrict__ sq,
    u16* __restrict__ we, float* __restrict__ be)
{
    const int b = blockIdx.y, oc = blockIdx.x * 64;
    __shared__ float mu[NC], rs[NC];
    __shared__ __align__(16) float wt[64 * NC];
    const int t = threadIdx.x;
    {
        const float m = sum[b*NC + t] * (1.0f / HW);
        const float v = sq[b*NC + t] * (1.0f / HW) - m * m;
        mu[t] = m;
        rs[t] = rsqrtf(v + 1e-5f);
    }
    #pragma unroll
    for (int i = 0; i < 16; ++i)
        *(float4*)&wt[i*1024 + t*4] = *(const float4*)&w[(size_t)oc*NC + i*1024 + t*4];
    __syncthreads();
    const int o = oc + (t >> 2), q = t & 3;
    const float* wrow = &wt[(t >> 2) * NC];
    u16* werow = we + ((size_t)b * NC + o) * NC;
    float bacc = 0.f;
    for (int cc = 0; cc < 8; ++cc) {
        alignas(16) u16 pk[8];
        #pragma unroll
        for (int jj = 0; jj < 8; ++jj) {
            const int c = q*64 + cc*8 + jj;
            const float wv = wrow[c];
            bacc -= wv * mu[c] * rs[c];
            pk[jj] = bf16bits(wv * rs[c]);
        }
        *(uint4*)(werow + q*64 + cc*8) = *(const uint4*)pk;
    }
    bacc += __shfl_xor(bacc, 1, 64);
    bacc += __shfl_xor(bacc, 2, 64);
    if (q == 0) be[b*NC + o] = bias[o] + bacc;
}

// ---------------- fused GEMM ----------------
// STAGE1: D[p][o] = relu(xt[p][:] . w1e[o][:] + b1e[o]) -> ht[b][p][o] bf16, + h stats atomics
// STAGE2: D[o][p] = relu(ht[p][:] . w2e[o][:] + b2e[o]) -> out[b][o][p] fp32 (NCHW)
template<int STAGE>
__global__ __launch_bounds__(256, 4) void gemm_kernel(
    const u16* __restrict__ smallM,   // pixel matrix [B*HW][NC] (xt or ht)
    const u16* __restrict__ bigM,     // weights [B*NC][NC] (w1e or w2e)
    const float* __restrict__ biasE,  // [B][NC]
    u16* __restrict__ outB,           // stage1: ht
    float* __restrict__ outF,         // stage2: out
    float* __restrict__ stSum, float* __restrict__ stSq)
{
    __shared__ __align__(16) u16 ldsS[64 * 32];    // small-mat slab: 64 rows x 32 bf16
    __shared__ __align__(16) u16 ldsB[NC * 32];    // big-mat slab: 256 rows x 32 bf16
    const int b = blockIdx.y;
    const int p0 = blockIdx.x * 64;
    const int tid = threadIdx.x;
    const int lane = tid & 63, wid = tid >> 6;
    const int l15 = lane & 15, l4 = lane >> 4;

    const u16* sTile = smallM + ((size_t)b * HW + p0) * NC;
    const u16* gB    = bigM + (size_t)b * NC * NC;

    f32x4 acc[4][4];
    #pragma unroll
    for (int i = 0; i < 4; ++i)
        #pragma unroll
        for (int j = 0; j < 4; ++j)
            acc[i][j] = (f32x4){0.f, 0.f, 0.f, 0.f};

    // staging lane constants: lane l covers row (chunk*16 + l/4), phys 16B slot l&3;
    // fetch the logical slot that belongs there (pre-swizzled global source, m173)
    const int rin  = lane >> 2;
    const int ssrc = ((lane & 3) ^ ((lane >> 2) & 3) ^ ((lane >> 4) & 3));

    for (int ks = 0; ks < 8; ++ks) {
        const int k0 = ks * 32;
        for (int j = wid; j < 20; j += 4) {
            if (j < 16) {
                const int row = j * 16 + rin;
                gload16(gB + (size_t)row * NC + k0 + ssrc * 8, (char*)ldsB + j * 1024);
            } else {
                const int row = (j - 16) * 16 + rin;
                gload16(sTile + (size_t)row * NC + k0 + ssrc * 8, (char*)ldsS + (j - 16) * 1024);
            }
        }
        __syncthreads();   // compiler emits vmcnt(0) drain before barrier

        const u16* slabM; const u16* slabN; int mOff, nOff;
        if constexpr (STAGE == 1) { slabM = ldsS; mOff = 0;        slabN = ldsB; nOff = 64 * wid; }
        else                      { slabM = ldsB; mOff = 64 * wid; slabN = ldsS; nOff = 0; }

        frag_ab a[4];
        #pragma unroll
        for (int mi = 0; mi < 4; ++mi)
            a[mi] = read_frag(slabM, mOff + 16*mi + l15, l4);
        #pragma unroll
        for (int ni = 0; ni < 4; ++ni) {
            const frag_ab bfr = read_frag(slabN, nOff + 16*ni + l15, l4);
            #pragma unroll
            for (int mi = 0; mi < 4; ++mi)
                acc[mi][ni] = __builtin_amdgcn_mfma_f32_16x16x32_bf16(a[mi], bfr, acc[mi][ni], 0, 0, 0);
        }
        __syncthreads();
    }

    if constexpr (STAGE == 1) {
        const int nBase = 64 * wid;
        u16* htp = outB + ((size_t)b * HW + p0) * NC;
        #pragma unroll
        for (int ni = 0; ni < 4; ++ni) {
            const int ncol = nBase + 16*ni + l15;
            const float bn = biasE[b*NC + ncol];
            float s1 = 0.f, s2 = 0.f;
            #pragma unroll
            for (int mi = 0; mi < 4; ++mi) {
                #pragma unroll
                for (int r = 0; r < 4; ++r) {
                    float v = acc[mi][ni][r] + bn;
                    v = fmaxf(v, 0.f);
                    s1 += v; s2 += v * v;
                    htp[(size_t)(16*mi + l4*4 + r) * NC + ncol] = bf16bits(v);
                }
            }
            s1 += __shfl_xor(s1, 16, 64); s1 += __shfl_xor(s1, 32, 64);
            s2 += __shfl_xor(s2, 16, 64); s2 += __shfl_xor(s2, 32, 64);
            if (l4 == 0) {
                atomicAdd(&stSum[b*NC + ncol], s1);
                atomicAdd(&stSq [b*NC + ncol], s2);
            }
        }
    } else {
        float* op = outF + ((size_t)b * NC + 64 * wid) * HW + p0;
        #pragma unroll
        for (int mi = 0; mi < 4; ++mi) {
            #pragma unroll
            for (int r = 0; r < 4; ++r) {
                const int orow = 16*mi + l4*4 + r;
                const float bm = biasE[b*NC + 64*wid + orow];
                #pragma unroll
                for (int ni = 0; ni < 4; ++ni) {
                    const float v = acc[mi][ni][r] + bm;
                    op[(size_t)orow * HW + 16*ni + l15] = fmaxf(v, 0.f);
                }
            }
        }
    }
}

extern "C" void kernel_launch(void* const* d_in, const int* in_sizes, int n_in,
                              void* d_out, int out_size, void* d_ws, size_t ws_size,
                              hipStream_t stream)
{
    (void)in_sizes; (void)n_in; (void)out_size;
    const float* x  = (const float*)d_in[0];
    const float* w1 = (const float*)d_in[1];
    const float* b1 = (const float*)d_in[2];
    const float* w2 = (const float*)d_in[3];
    const float* b2 = (const float*)d_in[4];
    float* out = (float*)d_out;

    // xt (bf16 transposed x) lives in d_out scratch space: dead before gemm2 overwrites d_out.
    u16* xt = (u16*)d_out;                     // 134,217,728 B (half of d_out)

    char* ws = (char*)d_ws;
    const size_t NEED = 138510336;
    if (ws_size < NEED) return;                // loud failure instead of corruption
    u16*   ht   = (u16*)(ws);                  // 134,217,728
    u16*   w1e  = (u16*)(ws + 134217728);      //   2,097,152
    u16*   w2e  = (u16*)(ws + 136314880);      //   2,097,152
    float* b1e  = (float*)(ws + 138412032);    //      16,384
    float* b2e  = (float*)(ws + 138428416);    //      16,384
    float* stats= (float*)(ws + 138444800);    //      65,536 (4 x 4096 f32)
    float* xsum = stats, *xsq = stats + 4096, *hsum = stats + 8192, *hsq = stats + 12288;

    hipMemsetAsync(stats, 0, 4 * 4096 * sizeof(float), stream);

    transpose_stats_kernel<<<dim3(HW/64, NC/64, 16), 256, 0, stream>>>(x, xt, xsum, xsq);
    fold_kernel<<<dim3(4, 16), 256, 0, stream>>>(w1, b1, xsum, xsq, w1e, b1e);
    gemm_kernel<1><<<dim3(HW/64, 16), 256, 0, stream>>>(xt, w1e, b1e, ht, nullptr, hsum, hsq);
    fold_kernel<<<dim3(4, 16), 256, 0, stream>>>(w2, b2, hsum, hsq, w2e, b2e);
    gemm_kernel<2><<<dim3(HW/64, 16), 256, 0, stream>>>(ht, w2e, b2e, nullptr, out, nullptr, nullptr);
}